// Round 9
// baseline (591.509 us; speedup 1.0000x reference)
//
#include <hip/hip_runtime.h>
#include <hip/hip_cooperative_groups.h>

namespace cg = cooperative_groups;

// Problem constants (complete bipartite proxy<->sample + self-loops)
#define PP 100    // proxies
#define NS 1024   // samples
#define NN 1124   // total nodes
#define DD 512    // feature dim
#define CC 100    // fc out dim
#define NTHR 256

__device__ __forceinline__ float lk(float v) { return v > 0.f ? v : 0.2f * v; }

struct Params {
  const float *x, *prox, *W1, *b1, *W2, *b2, *fcw, *fcb;
  float *out, *h2s;
  float *h1, *M1, *M2, *Ep, *esP, *izP;
  float *ls1, *ld1, *ls2, *ld2;          // ld = ls + 1152 (contiguous pairs)
  float *v1s, *v1d, *v2s, *v2d;
  const float *as1, *ad1, *as2, *ad2;
};

// ---- GEMM tile core. Krows: valid B rows (pad reads 0). k-major LDS.
// EPI: v=(acc+es[r]*S[r*N+c])*iz[r]. LV: epilogue accumulates h-row dot v2s/v2d
// into lsO/ldO via 16-lane shuffle + atomicAdd (fused layer-2 logits).
template<int BM, int BN, int TM, int TN, bool RELU, bool EPI, bool LV>
__device__ void gemm_dev(
    const float* __restrict__ A, int M, const float* __restrict__ B, int Krows,
    float* __restrict__ C, const float* __restrict__ bias, int K, int N,
    const float* __restrict__ S, const float* __restrict__ es,
    const float* __restrict__ iz, int row0, int col0, float* smem,
    const float* __restrict__ vs2, const float* __restrict__ vd2,
    float* __restrict__ lsO, float* __restrict__ ldO)
{
  constexpr int BK  = 32;
  constexpr int NCT = BN / TN;
  constexpr int AF4 = BM * BK / 4;
  constexpr int BF4 = BK * BN / 4;
  constexpr int AFP = (AF4 + NTHR - 1) / NTHR;
  constexpr int BFP = (BF4 + NTHR - 1) / NTHR;
  static_assert(NCT * (BM / TM) == NTHR, "bad tile");
  float* As = smem;
  float* Bs = smem + BK * BM;
  const int t  = threadIdx.x;
  const int tn = t % NCT, tm = t / NCT;
  float4 aR[AFP], bR[BFP];

  auto loadA = [&](int kt) {
    #pragma unroll
    for (int p = 0; p < AFP; ++p) {
      int f = t + p * NTHR;
      float4 v = {0.f, 0.f, 0.f, 0.f};
      if (f < AF4) {
        int m = f / (BK / 4), k4 = (f % (BK / 4)) * 4;
        int r = row0 + m;
        if (r < M) v = *(const float4*)(A + (size_t)r * K + kt + k4);
      }
      aR[p] = v;
    }
  };
  auto loadB = [&](int kt) {
    #pragma unroll
    for (int p = 0; p < BFP; ++p) {
      int f = t + p * NTHR;
      float4 v = {0.f, 0.f, 0.f, 0.f};
      if (f < BF4) {
        int k = kt + f / (BN / 4), c = col0 + (f % (BN / 4)) * 4;
        if (k < Krows && c + 3 < N) v = *(const float4*)(B + (size_t)k * N + c);
      }
      bR[p] = v;
    }
  };
  auto storeT = [&]() {
    #pragma unroll
    for (int p = 0; p < AFP; ++p) {
      int f = t + p * NTHR;
      if (f < AF4) {
        int m = f / (BK / 4), k4 = (f % (BK / 4)) * 4;
        As[(k4 + 0) * BM + m] = aR[p].x;
        As[(k4 + 1) * BM + m] = aR[p].y;
        As[(k4 + 2) * BM + m] = aR[p].z;
        As[(k4 + 3) * BM + m] = aR[p].w;
      }
    }
    #pragma unroll
    for (int p = 0; p < BFP; ++p) {
      int f = t + p * NTHR;
      if (f < BF4) {
        int k = f / (BN / 4), c4 = (f % (BN / 4)) * 4;
        *(float4*)(Bs + k * BN + c4) = bR[p];
      }
    }
  };

  float acc[TM][TN] = {};
  loadA(0); loadB(0); storeT();
  __syncthreads();
  for (int kt = BK; kt < K + BK; kt += BK) {
    const bool more = (kt < K);
    if (more) { loadA(kt); loadB(kt); }
    #pragma unroll
    for (int k = 0; k < BK; ++k) {
      float a[TM], b[TN];
      if constexpr (TM == 1) {
        a[0] = As[k * BM + tm];
      } else {
        float2 v = *(const float2*)(As + k * BM + tm * 2);
        a[0] = v.x; a[1] = v.y;
      }
      float4 bv = *(const float4*)(Bs + k * BN + tn * 4);
      b[0] = bv.x; b[1] = bv.y; b[2] = bv.z; b[3] = bv.w;
      #pragma unroll
      for (int i = 0; i < TM; ++i)
        #pragma unroll
        for (int j = 0; j < TN; ++j)
          acc[i][j] = fmaf(a[i], b[j], acc[i][j]);
    }
    __syncthreads();
    if (more) { storeT(); __syncthreads(); }
  }
  #pragma unroll
  for (int i = 0; i < TM; ++i) {
    int r = row0 + tm * TM + i;
    if (r >= M) continue;
    float esr = 0.f, izr = 0.f;
    if constexpr (EPI) { esr = es[r]; izr = iz[r]; }
    float p1 = 0.f, p2 = 0.f;
    #pragma unroll
    for (int j = 0; j < TN; ++j) {
      int c = col0 + tn * TN + j;
      if (c >= N) continue;
      float v = acc[i][j];
      if constexpr (EPI) v = (v + esr * S[(size_t)r * N + c]) * izr;
      if (bias) v += bias[c];
      if constexpr (RELU) v = fmaxf(v, 0.f);
      C[(size_t)r * N + c] = v;
      if constexpr (LV) { p1 = fmaf(v, vs2[c], p1); p2 = fmaf(v, vd2[c], p2); }
    }
    if constexpr (LV) {        // reduce across the 16 threads sharing row r
      #pragma unroll
      for (int off = 1; off < 16; off <<= 1) {
        p1 += __shfl_xor(p1, off);
        p2 += __shfl_xor(p2, off);
      }
      if ((t & 15) == 0) { atomicAdd(&lsO[r], p1); atomicAdd(&ldO[r], p2); }
    }
  }
}

// ---- sample-dst mix tile (32 rows x 64 cols), in-tile softmax stats --------
__device__ void mixS_tile(const float* __restrict__ ls, const float* __restrict__ ld,
                          const float* __restrict__ Bp, const float* __restrict__ Bself,
                          float* __restrict__ Mout, int row0, int col0, float* smem)
{
  float* Et    = smem;             // [32 k][32 r]
  float* Bs    = Et + 32 * 32;     // [32 k][64 c]
  float* lsP   = Bs + 32 * 64;     // [100]
  float* rowM  = lsP + 100;
  float* rowL  = rowM + 32;
  float* rowIZ = rowL + 32;
  float* rowES = rowIZ + 32;
  const int t = threadIdx.x;
  if (t < PP) lsP[t] = ls[t];
  __syncthreads();
  {
    const int r = t >> 3, q = t & 7;
    const int s = row0 + r;
    const float ldr = ld[PP + s];
    const float lself = ls[PP + s];
    float mx = -3.4e38f;
    for (int k = q; k < PP; k += 8) mx = fmaxf(mx, lsP[k]);
    mx = fmaxf(mx, __shfl_xor(mx, 1));
    mx = fmaxf(mx, __shfl_xor(mx, 2));
    mx = fmaxf(mx, __shfl_xor(mx, 4));
    mx = fmaxf(mx, lself);
    const float m = lk(mx + ldr);
    float z = 0.f;
    for (int k = q; k < PP; k += 8) z += __expf(lk(lsP[k] + ldr) - m);
    const float es = __expf(lk(lself + ldr) - m);
    if (q == 0) z += es;
    z += __shfl_xor(z, 1);
    z += __shfl_xor(z, 2);
    z += __shfl_xor(z, 4);
    if (q == 0) { rowM[r] = m; rowL[r] = ldr; rowIZ[r] = 1.f / z; rowES[r] = es; }
  }
  __syncthreads();
  const int tn = t % 16, tm = t / 16;
  float acc[2][4] = {};
  for (int k0 = 0; k0 < 128; k0 += 32) {
    #pragma unroll
    for (int p = 0; p < 4; ++p) {
      int f = t + p * 256;
      int kk = f >> 5, rr = f & 31;
      float e = 0.f;
      if (k0 + kk < PP) e = __expf(lk(lsP[k0 + kk] + rowL[rr]) - rowM[rr]);
      Et[kk * 32 + rr] = e;
    }
    #pragma unroll
    for (int p = 0; p < 2; ++p) {
      int f = t + p * 256;
      int kk = f / 16, cc = (f % 16) * 4;
      float4 v = {0.f, 0.f, 0.f, 0.f};
      if (k0 + kk < PP) v = *(const float4*)(Bp + (size_t)(k0 + kk) * DD + col0 + cc);
      *(float4*)(Bs + kk * 64 + cc) = v;
    }
    __syncthreads();
    #pragma unroll
    for (int k = 0; k < 32; ++k) {
      float2 av = *(const float2*)(Et + k * 32 + tm * 2);
      float4 bv = *(const float4*)(Bs + k * 64 + tn * 4);
      #pragma unroll
      for (int j = 0; j < 4; ++j) {
        acc[0][j] = fmaf(av.x, (&bv.x)[j], acc[0][j]);
        acc[1][j] = fmaf(av.y, (&bv.x)[j], acc[1][j]);
      }
    }
    __syncthreads();
  }
  #pragma unroll
  for (int i = 0; i < 2; ++i) {
    const int rl = tm * 2 + i, s = row0 + rl;
    const float izv = rowIZ[rl], esv = rowES[rl];
    float4 sv = *(const float4*)(Bself + (size_t)s * DD + col0 + tn * 4);
    #pragma unroll
    for (int j = 0; j < 4; ++j)
      Mout[(size_t)s * DD + col0 + tn * 4 + j] = (acc[i][j] + esv * (&sv.x)[j]) * izv;
  }
}

// ---- per-proxy softmax: stats + materialize Ep row (block per proxy) -------
__device__ void alphaP(const float* __restrict__ ls, const float* __restrict__ ld,
                       float* __restrict__ Ep, float* __restrict__ esP,
                       float* __restrict__ izP, int i, float* red)
{
  const int t = threadIdx.x;
  const float ldi = ld[i];
  const float eself = lk(ls[i] + ldi);
  float e[4];
  #pragma unroll
  for (int q = 0; q < 4; ++q) e[q] = lk(ls[PP + t + q * 256] + ldi);
  float m = fmaxf(fmaxf(fmaxf(e[0], e[1]), fmaxf(e[2], e[3])), eself);
  #pragma unroll
  for (int off = 1; off < 64; off <<= 1) m = fmaxf(m, __shfl_xor(m, off));
  if ((t & 63) == 0) red[t >> 6] = m;
  __syncthreads();
  m = fmaxf(fmaxf(red[0], red[1]), fmaxf(red[2], red[3]));
  __syncthreads();
  float xq[4], z = 0.f;
  #pragma unroll
  for (int q = 0; q < 4; ++q) { xq[q] = __expf(e[q] - m); z += xq[q]; }
  #pragma unroll
  for (int off = 1; off < 64; off <<= 1) z += __shfl_xor(z, off);
  if ((t & 63) == 0) red[t >> 6] = z;
  __syncthreads();
  #pragma unroll
  for (int q = 0; q < 4; ++q) Ep[(size_t)i * NS + t + q * 256] = xq[q];
  if (t == 0) {
    float xs = __expf(eself - m);
    esP[i] = xs;
    izP[i] = 1.f / (red[0] + red[1] + red[2] + red[3] + xs);
  }
  __syncthreads();
}

// ---- one wave: dual dot of 512-float row with two 512-float vectors --------
__device__ __forceinline__ void dualdot(const float* __restrict__ row,
                                        const float* __restrict__ va,
                                        const float* __restrict__ vb,
                                        int lane, float* o1, float* o2)
{
  const float4* r4 = (const float4*)row;
  const float4* a4 = (const float4*)va;
  const float4* b4 = (const float4*)vb;
  float4 v0 = r4[lane], v1 = r4[lane + 64];
  float4 a0 = a4[lane], a1 = a4[lane + 64];
  float4 b0 = b4[lane], b1 = b4[lane + 64];
  float s1 = v0.x*a0.x + v0.y*a0.y + v0.z*a0.z + v0.w*a0.w
           + v1.x*a1.x + v1.y*a1.y + v1.z*a1.z + v1.w*a1.w;
  float s2 = v0.x*b0.x + v0.y*b0.y + v0.z*b0.z + v0.w*b0.w
           + v1.x*b1.x + v1.y*b1.y + v1.z*b1.z + v1.w*b1.w;
  #pragma unroll
  for (int off = 32; off > 0; off >>= 1) {
    s1 += __shfl_down(s1, off);
    s2 += __shfl_down(s2, off);
  }
  *o1 = s1; *o2 = s2;
}

__global__ __launch_bounds__(NTHR, 2) void fused_gat(Params p)
{
  cg::grid_group grid = cg::this_grid();
  __shared__ float smem[3328];
  __shared__ float red[4];
  const int nb = gridDim.x, bid = blockIdx.x, t = threadIdx.x;
  const int wv = t >> 6, lane = t & 63;

  // S0: v = W@a (1024 wave-rows) + zero ls2/ld2 accumulators (2304 floats)
  for (int wid = bid * 4 + wv; wid < 1024; wid += nb * 4) {
    const int r = wid & 511;
    const bool l1 = (wid < 512);
    float s1, s2;
    dualdot((l1 ? p.W1 : p.W2) + (size_t)r * DD,
            l1 ? p.as1 : p.as2, l1 ? p.ad1 : p.ad2, lane, &s1, &s2);
    if (lane == 0) { (l1 ? p.v1s : p.v2s)[r] = s1; (l1 ? p.v1d : p.v2d)[r] = s2; }
  }
  for (int i = bid * NTHR + t; i < 2304; i += nb * NTHR) p.ls2[i] = 0.f;
  grid.sync();

  // S1: layer-1 logits (wave per row)
  for (int r = bid * 4 + wv; r < NN; r += nb * 4) {
    const float* row = (r < PP) ? p.prox + (size_t)r * DD
                                : p.x + (size_t)(r - PP) * DD;
    float s1, s2;
    dualdot(row, p.v1s, p.v1d, lane, &s1, &s2);
    if (lane == 0) { p.ls1[r] = s1; p.ld1[r] = s2; }
  }
  grid.sync();

  // S2: proxy alpha (100) + sample mix1 (256 tiles) -> M1 sample rows
  for (int tile = bid; tile < 356; tile += nb) {
    if (tile < 100)
      alphaP(p.ls1, p.ld1, p.Ep, p.esP, p.izP, tile, red);
    else {
      int q = tile - 100;
      mixS_tile(p.ls1, p.ld1, p.prox, p.x, p.M1 + (size_t)PP * DD,
                (q >> 3) * 32, (q & 7) * 64, smem);
    }
  }
  grid.sync();

  // S3: proxy agg (56 tiles) -> M1 proxy rows; gemm1 sample row-tiles 32..287
  //     gemm1 epilogue folds layer-2 logits (atomic).
  for (int tile = bid; tile < 312; tile += nb) {
    if (tile < 56)
      gemm_dev<16, 64, 1, 4, false, true, false>(
          p.Ep, PP, p.x, NS, p.M1, nullptr, NS, DD,
          p.prox, p.esP, p.izP, (tile >> 3) * 16, (tile & 7) * 64, smem,
          nullptr, nullptr, nullptr, nullptr);
    else {
      int q = tile - 56 + 32;   // row-tiles 4..35 (pure sample rows of M1)
      gemm_dev<32, 64, 2, 4, true, false, true>(
          p.M1, NN, p.W1, DD, p.h1, p.b1, DD, DD,
          nullptr, nullptr, nullptr, (q >> 3) * 32, (q & 7) * 64, smem,
          p.v2s, p.v2d, p.ls2, p.ld2);
    }
  }
  grid.sync();

  // S4: gemm1 row-tiles 0..3 (rows 0..127, needs M1 proxy rows from S3)
  for (int tile = bid; tile < 32; tile += nb)
    gemm_dev<32, 64, 2, 4, true, false, true>(
        p.M1, NN, p.W1, DD, p.h1, p.b1, DD, DD,
        nullptr, nullptr, nullptr, (tile >> 3) * 32, (tile & 7) * 64, smem,
        p.v2s, p.v2d, p.ls2, p.ld2);
  grid.sync();

  // S5: sample mix2 (256 tiles) -> M2  (layer-2 proxy rows are dead code)
  for (int tile = bid; tile < 256; tile += nb)
    mixS_tile(p.ls2, p.ld2, p.h1, p.h1 + (size_t)PP * DD, p.M2,
              (tile >> 3) * 32, (tile & 7) * 64, smem);
  grid.sync();

  // S6: h2s = relu(M2@W2 + b2) straight into d_out (256 tiles)
  for (int tile = bid; tile < 256; tile += nb)
    gemm_dev<32, 64, 2, 4, true, false, false>(
        p.M2, NS, p.W2, DD, p.h2s, p.b2, DD, DD,
        nullptr, nullptr, nullptr, (tile >> 3) * 32, (tile & 7) * 64, smem,
        nullptr, nullptr, nullptr, nullptr);
  grid.sync();

  // S7: preds = h2s @ fcw + fcb (64 tiles: 32 rows x 2 col-tiles)
  for (int tile = bid; tile < 64; tile += nb)
    gemm_dev<32, 64, 2, 4, false, false, false>(
        p.h2s, NS, p.fcw, DD, p.out, p.fcb, DD, CC,
        nullptr, nullptr, nullptr, (tile >> 1) * 32, (tile & 1) * 64, smem,
        nullptr, nullptr, nullptr, nullptr);
}

extern "C" void kernel_launch(void* const* d_in, const int* in_sizes, int n_in,
                              void* d_out, int out_size, void* d_ws, size_t ws_size,
                              hipStream_t stream)
{
  Params p;
  p.x    = (const float*)d_in[0];
  p.prox = (const float*)d_in[1];
  p.W1   = (const float*)d_in[2];
  p.as1  = (const float*)d_in[3];
  p.ad1  = (const float*)d_in[4];
  p.b1   = (const float*)d_in[5];
  p.W2   = (const float*)d_in[6];
  p.as2  = (const float*)d_in[7];
  p.ad2  = (const float*)d_in[8];
  p.b2   = (const float*)d_in[9];
  p.fcw  = (const float*)d_in[10];
  p.fcb  = (const float*)d_in[11];
  p.out  = (float*)d_out;
  p.h2s  = p.out + (size_t)NS * CC;

  float* base = (float*)d_ws;
  p.h1  = base;                                  // [1124][512]
  p.M1  = p.h1 + (size_t)NN * DD;                // [1124][512]
  p.M2  = p.M1 + (size_t)NN * DD;                // [1024][512]
  p.Ep  = p.M2 + (size_t)NS * DD;                // [100][1024]
  p.esP = p.Ep + (size_t)PP * NS;                // [128]
  p.izP = p.esP + 128;                           // [128]
  p.ls1 = p.izP + 128;  p.ld1 = p.ls1 + 1152;    // [1152] each
  p.ls2 = p.ld1 + 1152; p.ld2 = p.ls2 + 1152;    // ls2/ld2 contiguous (zeroed in S0)
  p.v1s = p.ld2 + 1152; p.v1d = p.v1s + DD;
  p.v2s = p.v1d + DD;   p.v2d = p.v2s + DD;

  // Cooperative launch: grid must be fully co-resident. 2 blocks/CU target.
  int bpc = 1;
  if (hipOccupancyMaxActiveBlocksPerMultiprocessor(&bpc, fused_gat, NTHR, 0)
      != hipSuccess || bpc < 1) bpc = 1;
  if (bpc > 2) bpc = 2;
  int nblk = 256 * bpc;                          // 256 or 512

  void* args[] = { (void*)&p };
  hipLaunchCooperativeKernel((const void*)fused_gat, dim3(nblk), dim3(NTHR),
                             args, 0, stream);
}

// Round 10
// 425.975 us; speedup vs baseline: 1.3886x; 1.3886x over previous
//
#include <hip/hip_runtime.h>

// Problem constants (complete bipartite proxy<->sample + self-loops)
#define PP 100    // proxies
#define NS 1024   // samples
#define NN 1124   // total nodes
#define DD 512    // feature dim
#define CC 100    // fc out dim
#define NTHR 256

__device__ __forceinline__ float lk(float v) { return v > 0.f ? v : 0.2f * v; }

// ============ GEMM kernel: C[M,N] = A[M,K]@B[K,N] (+bias, relu) =============
// LV: epilogue also accumulates row(C) . vs2 / vd2 into lsO/ldO (fused logits)
// via 16-lane shuffle + atomicAdd. K % 32 == 0. TN = 4.
template<int BM, int BN, int TM, bool RELU, bool LV>
__global__ __launch_bounds__(NTHR) void gemm_k(
    const float* __restrict__ A, int M, const float* __restrict__ B,
    float* __restrict__ C, const float* __restrict__ bias, int K, int N,
    const float* __restrict__ vs2, const float* __restrict__ vd2,
    float* __restrict__ lsO, float* __restrict__ ldO)
{
  constexpr int BK  = 32;
  constexpr int TN  = 4;
  constexpr int NCT = BN / TN;
  constexpr int AF4 = BM * BK / 4;
  constexpr int BF4 = BK * BN / 4;
  constexpr int AFP = (AF4 + NTHR - 1) / NTHR;
  constexpr int BFP = (BF4 + NTHR - 1) / NTHR;
  static_assert(NCT * (BM / TM) == NTHR, "bad tile");
  __shared__ float As[BK * BM];   // k-major
  __shared__ float Bs[BK * BN];
  const int row0 = blockIdx.y * BM;
  const int col0 = blockIdx.x * BN;
  const int t  = threadIdx.x;
  const int tn = t % NCT, tm = t / NCT;
  float4 aR[AFP], bR[BFP];

  auto loadA = [&](int kt) {
    #pragma unroll
    for (int p = 0; p < AFP; ++p) {
      int f = t + p * NTHR;
      float4 v = {0.f, 0.f, 0.f, 0.f};
      if (f < AF4) {
        int m = f / (BK / 4), k4 = (f % (BK / 4)) * 4;
        int r = row0 + m;
        if (r < M) v = *(const float4*)(A + (size_t)r * K + kt + k4);
      }
      aR[p] = v;
    }
  };
  auto loadB = [&](int kt) {
    #pragma unroll
    for (int p = 0; p < BFP; ++p) {
      int f = t + p * NTHR;
      float4 v = {0.f, 0.f, 0.f, 0.f};
      if (f < BF4) {
        int k = kt + f / (BN / 4), c = col0 + (f % (BN / 4)) * 4;
        if (c + 3 < N) v = *(const float4*)(B + (size_t)k * N + c);
      }
      bR[p] = v;
    }
  };
  auto storeT = [&]() {
    #pragma unroll
    for (int p = 0; p < AFP; ++p) {
      int f = t + p * NTHR;
      if (f < AF4) {
        int m = f / (BK / 4), k4 = (f % (BK / 4)) * 4;
        As[(k4 + 0) * BM + m] = aR[p].x;
        As[(k4 + 1) * BM + m] = aR[p].y;
        As[(k4 + 2) * BM + m] = aR[p].z;
        As[(k4 + 3) * BM + m] = aR[p].w;
      }
    }
    #pragma unroll
    for (int p = 0; p < BFP; ++p) {
      int f = t + p * NTHR;
      if (f < BF4) {
        int k = f / (BN / 4), c4 = (f % (BN / 4)) * 4;
        *(float4*)(Bs + k * BN + c4) = bR[p];
      }
    }
  };

  float acc[TM][TN] = {};
  loadA(0); loadB(0); storeT();
  __syncthreads();
  for (int kt = BK; kt < K + BK; kt += BK) {
    const bool more = (kt < K);
    if (more) { loadA(kt); loadB(kt); }
    #pragma unroll
    for (int k = 0; k < BK; ++k) {
      float a[TM], b[TN];
      if constexpr (TM == 1) {
        a[0] = As[k * BM + tm];
      } else {
        float2 v = *(const float2*)(As + k * BM + tm * 2);
        a[0] = v.x; a[1] = v.y;
      }
      float4 bv = *(const float4*)(Bs + k * BN + tn * 4);
      b[0] = bv.x; b[1] = bv.y; b[2] = bv.z; b[3] = bv.w;
      #pragma unroll
      for (int i = 0; i < TM; ++i)
        #pragma unroll
        for (int j = 0; j < TN; ++j)
          acc[i][j] = fmaf(a[i], b[j], acc[i][j]);
    }
    __syncthreads();
    if (more) { storeT(); __syncthreads(); }
  }
  #pragma unroll
  for (int i = 0; i < TM; ++i) {
    int r = row0 + tm * TM + i;
    if (r >= M) continue;
    float p1 = 0.f, p2 = 0.f;
    #pragma unroll
    for (int j = 0; j < TN; ++j) {
      int c = col0 + tn * TN + j;
      if (c >= N) continue;
      float v = acc[i][j] + bias[c];
      if constexpr (RELU) v = fmaxf(v, 0.f);
      C[(size_t)r * N + c] = v;
      if constexpr (LV) { p1 = fmaf(v, vs2[c], p1); p2 = fmaf(v, vd2[c], p2); }
    }
    if constexpr (LV) {        // reduce across the 16 threads sharing row r
      #pragma unroll
      for (int off = 1; off < 16; off <<= 1) {
        p1 += __shfl_xor(p1, off);
        p2 += __shfl_xor(p2, off);
      }
      if ((t & 15) == 0) { atomicAdd(&lsO[r], p1); atomicAdd(&ldO[r], p2); }
    }
  }
}

// ============ sample-dst mix tile (32 rows x 64 cols), in-tile stats ========
// M[s,:] = invZ_s * (Sum_p exp_sp * Bp[p,:] + es_s * Bself[s,:])
__device__ void mixS_tile(const float* __restrict__ ls, const float* __restrict__ ld,
                          const float* __restrict__ Bp, const float* __restrict__ Bself,
                          float* __restrict__ Mout, int row0, int col0, float* smem)
{
  float* Et    = smem;             // [32 k][32 r]
  float* Bs    = Et + 32 * 32;     // [32 k][64 c]
  float* lsP   = Bs + 32 * 64;     // [100]
  float* rowM  = lsP + 100;
  float* rowL  = rowM + 32;
  float* rowIZ = rowL + 32;
  float* rowES = rowIZ + 32;
  const int t = threadIdx.x;
  if (t < PP) lsP[t] = ls[t];
  __syncthreads();
  {                                // stats: 8 threads per dst row
    const int r = t >> 3, q = t & 7;
    const int s = row0 + r;
    const float ldr = ld[PP + s];
    const float lself = ls[PP + s];
    float mx = -3.4e38f;
    for (int k = q; k < PP; k += 8) mx = fmaxf(mx, lsP[k]);
    mx = fmaxf(mx, __shfl_xor(mx, 1));
    mx = fmaxf(mx, __shfl_xor(mx, 2));
    mx = fmaxf(mx, __shfl_xor(mx, 4));
    mx = fmaxf(mx, lself);
    const float m = lk(mx + ldr);  // leaky monotone -> exact segment max
    float z = 0.f;
    for (int k = q; k < PP; k += 8) z += __expf(lk(lsP[k] + ldr) - m);
    const float es = __expf(lk(lself + ldr) - m);
    if (q == 0) z += es;
    z += __shfl_xor(z, 1);
    z += __shfl_xor(z, 2);
    z += __shfl_xor(z, 4);
    if (q == 0) { rowM[r] = m; rowL[r] = ldr; rowIZ[r] = 1.f / z; rowES[r] = es; }
  }
  __syncthreads();
  const int tn = t % 16, tm = t / 16;
  float acc[2][4] = {};
  for (int k0 = 0; k0 < 128; k0 += 32) {     // K = 100 padded to 128
    #pragma unroll
    for (int p = 0; p < 4; ++p) {            // Et on the fly
      int f = t + p * 256;
      int kk = f >> 5, rr = f & 31;
      float e = 0.f;
      if (k0 + kk < PP) e = __expf(lk(lsP[k0 + kk] + rowL[rr]) - rowM[rr]);
      Et[kk * 32 + rr] = e;
    }
    #pragma unroll
    for (int p = 0; p < 2; ++p) {            // Bs[32][64]
      int f = t + p * 256;
      int kk = f / 16, cc = (f % 16) * 4;
      float4 v = {0.f, 0.f, 0.f, 0.f};
      if (k0 + kk < PP) v = *(const float4*)(Bp + (size_t)(k0 + kk) * DD + col0 + cc);
      *(float4*)(Bs + kk * 64 + cc) = v;
    }
    __syncthreads();
    #pragma unroll
    for (int k = 0; k < 32; ++k) {
      float2 av = *(const float2*)(Et + k * 32 + tm * 2);
      float4 bv = *(const float4*)(Bs + k * 64 + tn * 4);
      #pragma unroll
      for (int j = 0; j < 4; ++j) {
        acc[0][j] = fmaf(av.x, (&bv.x)[j], acc[0][j]);
        acc[1][j] = fmaf(av.y, (&bv.x)[j], acc[1][j]);
      }
    }
    __syncthreads();
  }
  #pragma unroll
  for (int i = 0; i < 2; ++i) {
    const int rl = tm * 2 + i, s = row0 + rl;
    const float izv = rowIZ[rl], esv = rowES[rl];
    float4 sv = *(const float4*)(Bself + (size_t)s * DD + col0 + tn * 4);
    #pragma unroll
    for (int j = 0; j < 4; ++j)
      Mout[(size_t)s * DD + col0 + tn * 4 + j] = (acc[i][j] + esv * (&sv.x)[j]) * izv;
  }
}

// ============ proxy-dst mix tile (16 rows x 64 cols), PARALLEL in-tile stats =
// M[p,:] = invZ_p * (Sum_s exp_ps * X[s,:] + es_p * Pr[p,:]); K = 1024 samples.
// Stats: 16 threads per row, 64-iteration strided reductions (L2-hot ls).
__device__ void mixP_tile(const float* __restrict__ ls, const float* __restrict__ ld,
                          const float* __restrict__ X, const float* __restrict__ Pr,
                          float* __restrict__ Mout, int row0, int col0, float* smem)
{
  float* Et    = smem;             // [32 k][16 r]
  float* Bs    = Et + 32 * 16;     // [32 k][64 c]
  float* rowM  = Bs + 32 * 64;     // [16]
  float* rowL  = rowM + 16;
  float* rowIZ = rowL + 16;
  float* rowES = rowIZ + 16;
  const int t = threadIdx.x;
  {                                // stats: 16 threads per dst row
    const int r = t >> 4, q = t & 15;
    const int p = row0 + r;
    const bool ok = (p < PP);
    const float ldr = ok ? ld[p] : 0.f;
    const float lself = ok ? ls[p] : 0.f;
    float mx = -3.4e38f;
    for (int k = q; k < NS; k += 16) mx = fmaxf(mx, ls[PP + k]);
    mx = fmaxf(mx, __shfl_xor(mx, 1));
    mx = fmaxf(mx, __shfl_xor(mx, 2));
    mx = fmaxf(mx, __shfl_xor(mx, 4));
    mx = fmaxf(mx, __shfl_xor(mx, 8));
    mx = fmaxf(mx, lself);
    const float m = lk(mx + ldr);
    float z = 0.f;
    for (int k = q; k < NS; k += 16) z += __expf(lk(ls[PP + k] + ldr) - m);
    const float es = __expf(lk(lself + ldr) - m);
    if (q == 0) z += es;
    z += __shfl_xor(z, 1);
    z += __shfl_xor(z, 2);
    z += __shfl_xor(z, 4);
    z += __shfl_xor(z, 8);
    if (q == 0) { rowM[r] = m; rowL[r] = ldr; rowIZ[r] = 1.f / z; rowES[r] = es; }
  }
  __syncthreads();
  const int tn = t % 16, tm = t / 16;   // tm = row 0..15, TN = 4 cols
  float acc[4] = {};
  for (int k0 = 0; k0 < NS; k0 += 32) {
    #pragma unroll
    for (int p4 = 0; p4 < 2; ++p4) {    // Et[32][16] on the fly
      int f = t + p4 * 256;
      int kk = f >> 4, rr = f & 15;
      float e = 0.f;
      if (row0 + rr < PP) e = __expf(lk(ls[PP + k0 + kk] + rowL[rr]) - rowM[rr]);
      Et[kk * 16 + rr] = e;
    }
    #pragma unroll
    for (int p4 = 0; p4 < 2; ++p4) {    // Bs[32][64]
      int f = t + p4 * 256;
      int kk = f / 16, cc = (f % 16) * 4;
      *(float4*)(Bs + kk * 64 + cc) =
          *(const float4*)(X + (size_t)(k0 + kk) * DD + col0 + cc);
    }
    __syncthreads();
    #pragma unroll
    for (int k = 0; k < 32; ++k) {
      float av = Et[k * 16 + tm];
      float4 bv = *(const float4*)(Bs + k * 64 + tn * 4);
      #pragma unroll
      for (int j = 0; j < 4; ++j) acc[j] = fmaf(av, (&bv.x)[j], acc[j]);
    }
    __syncthreads();
  }
  const int p = row0 + tm;
  if (p < PP) {
    const float izv = rowIZ[tm], esv = rowES[tm];
    float4 sv = *(const float4*)(Pr + (size_t)p * DD + col0 + tn * 4);
    #pragma unroll
    for (int j = 0; j < 4; ++j)
      Mout[(size_t)p * DD + col0 + tn * 4 + j] = (acc[j] + esv * (&sv.x)[j]) * izv;
  }
}

// layer-1 mix: blocks [0,256) sample tiles; [256,312) proxy tiles
__global__ __launch_bounds__(NTHR) void mix1_k(
    const float* __restrict__ ls, const float* __restrict__ ld,
    const float* __restrict__ x, const float* __restrict__ prox,
    float* __restrict__ M1)
{
  __shared__ float smem[3300];
  const int b = blockIdx.x;
  if (b < 256)
    mixS_tile(ls, ld, prox, x, M1 + (size_t)PP * DD, (b >> 3) * 32, (b & 7) * 64, smem);
  else {
    int b2 = b - 256;
    mixP_tile(ls, ld, x, prox, M1, (b2 >> 3) * 16, (b2 & 7) * 64, smem);
  }
}

// layer-2 mix (sample dsts only; layer-2 proxy rows are dead code)
__global__ __launch_bounds__(NTHR) void mix2_k(
    const float* __restrict__ ls, const float* __restrict__ ld,
    const float* __restrict__ h1, float* __restrict__ M2)
{
  __shared__ float smem[3300];
  const int b = blockIdx.x;
  mixS_tile(ls, ld, h1, h1 + (size_t)PP * DD, M2, (b >> 3) * 32, (b & 7) * 64, smem);
}

// ---- one wave: dual dot of 512-float row with two 512-float vectors --------
__device__ __forceinline__ void dualdot(const float* __restrict__ row,
                                        const float* __restrict__ va,
                                        const float* __restrict__ vb,
                                        int lane, float* o1, float* o2)
{
  const float4* r4 = (const float4*)row;
  const float4* a4 = (const float4*)va;
  const float4* b4 = (const float4*)vb;
  float4 v0 = r4[lane], v1 = r4[lane + 64];
  float4 a0 = a4[lane], a1 = a4[lane + 64];
  float4 b0 = b4[lane], b1 = b4[lane + 64];
  float s1 = v0.x*a0.x + v0.y*a0.y + v0.z*a0.z + v0.w*a0.w
           + v1.x*a1.x + v1.y*a1.y + v1.z*a1.z + v1.w*a1.w;
  float s2 = v0.x*b0.x + v0.y*b0.y + v0.z*b0.z + v0.w*b0.w
           + v1.x*b1.x + v1.y*b1.y + v1.z*b1.z + v1.w*b1.w;
  #pragma unroll
  for (int off = 32; off > 0; off >>= 1) {
    s1 += __shfl_down(s1, off);
    s2 += __shfl_down(s2, off);
  }
  *o1 = s1; *o2 = s2;
}

// K1: v = W@a for both layers (1024 wave-rows) + zero ls2/ld2 (2304 floats)
__global__ __launch_bounds__(NTHR) void matvec_k(
    const float* __restrict__ W1, const float* __restrict__ as1,
    const float* __restrict__ ad1,
    const float* __restrict__ W2, const float* __restrict__ as2,
    const float* __restrict__ ad2,
    float* __restrict__ v1s, float* __restrict__ v1d,
    float* __restrict__ v2s, float* __restrict__ v2d,
    float* __restrict__ zbuf)
{
  const int wid  = blockIdx.x * 4 + (threadIdx.x >> 6);  // 0..1023
  const int lane = threadIdx.x & 63;
  const int r = wid & 511;
  const bool l1 = (wid < 512);
  float s1, s2;
  dualdot((l1 ? W1 : W2) + (size_t)r * DD, l1 ? as1 : as2, l1 ? ad1 : ad2,
          lane, &s1, &s2);
  if (lane == 0) { (l1 ? v1s : v2s)[r] = s1; (l1 ? v1d : v2d)[r] = s2; }
  for (int i = blockIdx.x * NTHR + threadIdx.x; i < 2304; i += 256 * NTHR)
    zbuf[i] = 0.f;
}

// K2: layer-1 logits (wave per row)
__global__ __launch_bounds__(NTHR) void lvec_k(
    const float* __restrict__ prox, const float* __restrict__ x,
    const float* __restrict__ vs, const float* __restrict__ vd,
    float* __restrict__ ls, float* __restrict__ ld)
{
  const int r    = blockIdx.x * 4 + (threadIdx.x >> 6);
  const int lane = threadIdx.x & 63;
  if (r >= NN) return;
  const float* row = (r < PP) ? prox + (size_t)r * DD : x + (size_t)(r - PP) * DD;
  float s1, s2;
  dualdot(row, vs, vd, lane, &s1, &s2);
  if (lane == 0) { ls[r] = s1; ld[r] = s2; }
}

extern "C" void kernel_launch(void* const* d_in, const int* in_sizes, int n_in,
                              void* d_out, int out_size, void* d_ws, size_t ws_size,
                              hipStream_t stream)
{
  const float* x    = (const float*)d_in[0];
  const float* prox = (const float*)d_in[1];
  const float* W1   = (const float*)d_in[2];
  const float* as1  = (const float*)d_in[3];
  const float* ad1  = (const float*)d_in[4];
  const float* b1   = (const float*)d_in[5];
  const float* W2   = (const float*)d_in[6];
  const float* as2  = (const float*)d_in[7];
  const float* ad2  = (const float*)d_in[8];
  const float* b2   = (const float*)d_in[9];
  const float* fcw  = (const float*)d_in[10];
  const float* fcb  = (const float*)d_in[11];
  float* out = (float*)d_out;

  float* h1  = (float*)d_ws;                     // [1124][512]
  float* M1  = h1  + (size_t)NN * DD;            // [1124][512]
  float* M2  = M1  + (size_t)NN * DD;            // [1024][512]
  float* ls1 = M2  + (size_t)NS * DD;            // [1152]
  float* ld1 = ls1 + 1152;
  float* ls2 = ld1 + 1152;                       // ls2/ld2 contiguous (zeroed in K1)
  float* ld2 = ls2 + 1152;
  float* v1s = ld2 + 1152;
  float* v1d = v1s + DD;
  float* v2s = v1d + DD;
  float* v2d = v2s + DD;
  float* h2s = out + (size_t)NS * CC;            // layer-2 sample out in d_out

  dim3 blk(NTHR);
  // K1: weight-side matvecs (both layers) + zero ls2/ld2
  matvec_k<<<dim3(256), blk, 0, stream>>>(W1, as1, ad1, W2, as2, ad2,
                                          v1s, v1d, v2s, v2d, ls2);
  // K2: layer-1 logits
  lvec_k<<<dim3(281), blk, 0, stream>>>(prox, x, v1s, v1d, ls1, ld1);
  // K3: layer-1 mix (sample + proxy dsts, in-tile softmax stats) -> M1
  mix1_k<<<dim3(312), blk, 0, stream>>>(ls1, ld1, x, prox, M1);
  // K4: h1 = relu(M1@W1 + b1); epilogue fuses layer-2 logits into ls2/ld2
  gemm_k<32, 64, 2, true, true><<<dim3(8, 36), blk, 0, stream>>>(
      M1, NN, W1, h1, b1, DD, DD, v2s, v2d, ls2, ld2);
  // K5: layer-2 mix (sample dsts only) -> M2
  mix2_k<<<dim3(256), blk, 0, stream>>>(ls2, ld2, h1, M2);
  // K6: h2s = relu(M2@W2 + b2) straight into d_out
  gemm_k<32, 64, 2, true, false><<<dim3(8, 32), blk, 0, stream>>>(
      M2, NS, W2, h2s, b2, DD, DD, nullptr, nullptr, nullptr, nullptr);
  // K7: preds = h2s @ fcw + fcb   (16-row tiles for parallelism: 2 x 64)
  gemm_k<16, 64, 1, false, false><<<dim3(2, 64), blk, 0, stream>>>(
      h2s, NS, fcw, out, fcb, DD, CC, nullptr, nullptr, nullptr, nullptr);
}

// Round 11
// 411.610 us; speedup vs baseline: 1.4371x; 1.0349x over previous
//
#include <hip/hip_runtime.h>

// Problem constants (complete bipartite proxy<->sample + self-loops)
#define PP 100    // proxies
#define NS 1024   // samples
#define NN 1124   // total nodes
#define DD 512    // feature dim
#define CC 100    // fc out dim
#define NTHR 256

__device__ __forceinline__ float lk(float v) { return v > 0.f ? v : 0.2f * v; }

// ============ GEMM kernel: C[M,N] = A[M,K]@B[K,N] (+bias, relu) =============
// LV: epilogue also accumulates row(C) . vs2 / vd2 into lsO/ldO (fused logits)
// via 16-lane shuffle + atomicAdd. K % 32 == 0. TN = 4.
template<int BM, int BN, int TM, bool RELU, bool LV>
__global__ __launch_bounds__(NTHR) void gemm_k(
    const float* __restrict__ A, int M, const float* __restrict__ B,
    float* __restrict__ C, const float* __restrict__ bias, int K, int N,
    const float* __restrict__ vs2, const float* __restrict__ vd2,
    float* __restrict__ lsO, float* __restrict__ ldO)
{
  constexpr int BK  = 32;
  constexpr int TN  = 4;
  constexpr int NCT = BN / TN;
  constexpr int AF4 = BM * BK / 4;
  constexpr int BF4 = BK * BN / 4;
  constexpr int AFP = (AF4 + NTHR - 1) / NTHR;
  constexpr int BFP = (BF4 + NTHR - 1) / NTHR;
  static_assert(NCT * (BM / TM) == NTHR, "bad tile");
  __shared__ float As[BK * BM];   // k-major
  __shared__ float Bs[BK * BN];
  const int row0 = blockIdx.y * BM;
  const int col0 = blockIdx.x * BN;
  const int t  = threadIdx.x;
  const int tn = t % NCT, tm = t / NCT;
  float4 aR[AFP], bR[BFP];

  auto loadA = [&](int kt) {
    #pragma unroll
    for (int p = 0; p < AFP; ++p) {
      int f = t + p * NTHR;
      float4 v = {0.f, 0.f, 0.f, 0.f};
      if (f < AF4) {
        int m = f / (BK / 4), k4 = (f % (BK / 4)) * 4;
        int r = row0 + m;
        if (r < M) v = *(const float4*)(A + (size_t)r * K + kt + k4);
      }
      aR[p] = v;
    }
  };
  auto loadB = [&](int kt) {
    #pragma unroll
    for (int p = 0; p < BFP; ++p) {
      int f = t + p * NTHR;
      float4 v = {0.f, 0.f, 0.f, 0.f};
      if (f < BF4) {
        int k = kt + f / (BN / 4), c = col0 + (f % (BN / 4)) * 4;
        if (c + 3 < N) v = *(const float4*)(B + (size_t)k * N + c);
      }
      bR[p] = v;
    }
  };
  auto storeT = [&]() {
    #pragma unroll
    for (int p = 0; p < AFP; ++p) {
      int f = t + p * NTHR;
      if (f < AF4) {
        int m = f / (BK / 4), k4 = (f % (BK / 4)) * 4;
        As[(k4 + 0) * BM + m] = aR[p].x;
        As[(k4 + 1) * BM + m] = aR[p].y;
        As[(k4 + 2) * BM + m] = aR[p].z;
        As[(k4 + 3) * BM + m] = aR[p].w;
      }
    }
    #pragma unroll
    for (int p = 0; p < BFP; ++p) {
      int f = t + p * NTHR;
      if (f < BF4) {
        int k = f / (BN / 4), c4 = (f % (BN / 4)) * 4;
        *(float4*)(Bs + k * BN + c4) = bR[p];
      }
    }
  };

  float acc[TM][TN] = {};
  loadA(0); loadB(0); storeT();
  __syncthreads();
  for (int kt = BK; kt < K + BK; kt += BK) {
    const bool more = (kt < K);
    if (more) { loadA(kt); loadB(kt); }
    #pragma unroll
    for (int k = 0; k < BK; ++k) {
      float a[TM], b[TN];
      if constexpr (TM == 1) {
        a[0] = As[k * BM + tm];
      } else {
        float2 v = *(const float2*)(As + k * BM + tm * 2);
        a[0] = v.x; a[1] = v.y;
      }
      float4 bv = *(const float4*)(Bs + k * BN + tn * 4);
      b[0] = bv.x; b[1] = bv.y; b[2] = bv.z; b[3] = bv.w;
      #pragma unroll
      for (int i = 0; i < TM; ++i)
        #pragma unroll
        for (int j = 0; j < TN; ++j)
          acc[i][j] = fmaf(a[i], b[j], acc[i][j]);
    }
    __syncthreads();
    if (more) { storeT(); __syncthreads(); }
  }
  #pragma unroll
  for (int i = 0; i < TM; ++i) {
    int r = row0 + tm * TM + i;
    if (r >= M) continue;
    float p1 = 0.f, p2 = 0.f;
    #pragma unroll
    for (int j = 0; j < TN; ++j) {
      int c = col0 + tn * TN + j;
      if (c >= N) continue;
      float v = acc[i][j] + bias[c];
      if constexpr (RELU) v = fmaxf(v, 0.f);
      C[(size_t)r * N + c] = v;
      if constexpr (LV) { p1 = fmaf(v, vs2[c], p1); p2 = fmaf(v, vd2[c], p2); }
    }
    if constexpr (LV) {        // reduce across the 16 threads sharing row r
      #pragma unroll
      for (int off = 1; off < 16; off <<= 1) {
        p1 += __shfl_xor(p1, off);
        p2 += __shfl_xor(p2, off);
      }
      if ((t & 15) == 0) { atomicAdd(&lsO[r], p1); atomicAdd(&ldO[r], p2); }
    }
  }
}

// ============ sample-dst mix tile (32 rows x 64 cols), in-tile stats ========
// M[s,:] = invZ_s * (Sum_p exp_sp * Bp[p,:] + es_s * Bself[s,:])
__device__ void mixS_tile(const float* __restrict__ ls, const float* __restrict__ ld,
                          const float* __restrict__ Bp, const float* __restrict__ Bself,
                          float* __restrict__ Mout, int row0, int col0, float* smem)
{
  float* Et    = smem;             // [32 k][32 r]
  float* Bs    = Et + 32 * 32;     // [32 k][64 c]
  float* lsP   = Bs + 32 * 64;     // [100]
  float* rowM  = lsP + 100;
  float* rowL  = rowM + 32;
  float* rowIZ = rowL + 32;
  float* rowES = rowIZ + 32;
  const int t = threadIdx.x;
  if (t < PP) lsP[t] = ls[t];
  __syncthreads();
  {                                // stats: 8 threads per dst row
    const int r = t >> 3, q = t & 7;
    const int s = row0 + r;
    const float ldr = ld[PP + s];
    const float lself = ls[PP + s];
    float mx = -3.4e38f;
    #pragma clang loop unroll_count(4)
    for (int k = q; k < PP; k += 8) mx = fmaxf(mx, lsP[k]);
    mx = fmaxf(mx, __shfl_xor(mx, 1));
    mx = fmaxf(mx, __shfl_xor(mx, 2));
    mx = fmaxf(mx, __shfl_xor(mx, 4));
    mx = fmaxf(mx, lself);
    const float m = lk(mx + ldr);  // leaky monotone -> exact segment max
    float z = 0.f;
    #pragma clang loop unroll_count(4)
    for (int k = q; k < PP; k += 8) z += __expf(lk(lsP[k] + ldr) - m);
    const float es = __expf(lk(lself + ldr) - m);
    if (q == 0) z += es;
    z += __shfl_xor(z, 1);
    z += __shfl_xor(z, 2);
    z += __shfl_xor(z, 4);
    if (q == 0) { rowM[r] = m; rowL[r] = ldr; rowIZ[r] = 1.f / z; rowES[r] = es; }
  }
  __syncthreads();
  const int tn = t % 16, tm = t / 16;
  float acc[2][4] = {};
  for (int k0 = 0; k0 < 128; k0 += 32) {     // K = 100 padded to 128
    #pragma unroll
    for (int p = 0; p < 4; ++p) {            // Et on the fly
      int f = t + p * 256;
      int kk = f >> 5, rr = f & 31;
      float e = 0.f;
      if (k0 + kk < PP) e = __expf(lk(lsP[k0 + kk] + rowL[rr]) - rowM[rr]);
      Et[kk * 32 + rr] = e;
    }
    #pragma unroll
    for (int p = 0; p < 2; ++p) {            // Bs[32][64]
      int f = t + p * 256;
      int kk = f / 16, cc = (f % 16) * 4;
      float4 v = {0.f, 0.f, 0.f, 0.f};
      if (k0 + kk < PP) v = *(const float4*)(Bp + (size_t)(k0 + kk) * DD + col0 + cc);
      *(float4*)(Bs + kk * 64 + cc) = v;
    }
    __syncthreads();
    #pragma unroll
    for (int k = 0; k < 32; ++k) {
      float2 av = *(const float2*)(Et + k * 32 + tm * 2);
      float4 bv = *(const float4*)(Bs + k * 64 + tn * 4);
      #pragma unroll
      for (int j = 0; j < 4; ++j) {
        acc[0][j] = fmaf(av.x, (&bv.x)[j], acc[0][j]);
        acc[1][j] = fmaf(av.y, (&bv.x)[j], acc[1][j]);
      }
    }
    __syncthreads();
  }
  #pragma unroll
  for (int i = 0; i < 2; ++i) {
    const int rl = tm * 2 + i, s = row0 + rl;
    const float izv = rowIZ[rl], esv = rowES[rl];
    float4 sv = *(const float4*)(Bself + (size_t)s * DD + col0 + tn * 4);
    #pragma unroll
    for (int j = 0; j < 4; ++j)
      Mout[(size_t)s * DD + col0 + tn * 4 + j] = (acc[i][j] + esv * (&sv.x)[j]) * izv;
  }
}

// ============ proxy-dst mix tile (16 rows x 64 cols) =========================
// M[p,:] = invZ_p * (Sum_s exp_ps * X[s,:] + es_p * Pr[p,:]); K = 1024 samples.
// ALL stats/Et reads go through LDS-staged lsS[1024] with bounded unrolling —
// R10's global-strided stats loops fully unrolled, spilled (VGPR=256, 320 MB
// scratch traffic, 168 us). LDS staging removes the in-flight-load pressure.
__device__ void mixP_tile(const float* __restrict__ ls, const float* __restrict__ ld,
                          const float* __restrict__ X, const float* __restrict__ Pr,
                          float* __restrict__ Mout, int row0, int col0, float* smem)
{
  float* Et    = smem;             // [32 k][16 r]
  float* Bs    = Et + 32 * 16;     // [32 k][64 c]
  float* lsS   = Bs + 32 * 64;     // [1024] sample-side ls, staged
  float* rowM  = lsS + 1024;       // [16]
  float* rowL  = rowM + 16;
  float* rowIZ = rowL + 16;
  float* rowES = rowIZ + 16;
  const int t = threadIdx.x;
  // stage ls[PP .. PP+1024) -> LDS (256 float4 loads, one per thread; 400%16==0)
  ((float4*)lsS)[t] = *(const float4*)(ls + PP + t * 4);
  __syncthreads();
  {                                // stats: 16 threads per dst row, LDS reads
    const int r = t >> 4, q = t & 15;
    const int p = row0 + r;
    const bool ok = (p < PP);
    const float ldr = ok ? ld[p] : 0.f;
    const float lself = ok ? ls[p] : 0.f;
    float mx = -3.4e38f;
    #pragma clang loop unroll_count(4)
    for (int k = q; k < NS; k += 16) mx = fmaxf(mx, lsS[k]);
    mx = fmaxf(mx, __shfl_xor(mx, 1));
    mx = fmaxf(mx, __shfl_xor(mx, 2));
    mx = fmaxf(mx, __shfl_xor(mx, 4));
    mx = fmaxf(mx, __shfl_xor(mx, 8));
    mx = fmaxf(mx, lself);
    const float m = lk(mx + ldr);
    float z = 0.f;
    #pragma clang loop unroll_count(4)
    for (int k = q; k < NS; k += 16) z += __expf(lk(lsS[k] + ldr) - m);
    const float es = __expf(lk(lself + ldr) - m);
    if (q == 0) z += es;
    z += __shfl_xor(z, 1);
    z += __shfl_xor(z, 2);
    z += __shfl_xor(z, 4);
    z += __shfl_xor(z, 8);
    if (q == 0) { rowM[r] = m; rowL[r] = ldr; rowIZ[r] = 1.f / z; rowES[r] = es; }
  }
  __syncthreads();
  const int tn = t % 16, tm = t / 16;   // tm = row 0..15, TN = 4 cols
  float acc[4] = {};
  for (int k0 = 0; k0 < NS; k0 += 32) {
    #pragma unroll
    for (int p4 = 0; p4 < 2; ++p4) {    // Et[32][16] on the fly (LDS source)
      int f = t + p4 * 256;
      int kk = f >> 4, rr = f & 15;
      float e = 0.f;
      if (row0 + rr < PP) e = __expf(lk(lsS[k0 + kk] + rowL[rr]) - rowM[rr]);
      Et[kk * 16 + rr] = e;
    }
    #pragma unroll
    for (int p4 = 0; p4 < 2; ++p4) {    // Bs[32][64]
      int f = t + p4 * 256;
      int kk = f / 16, cc = (f % 16) * 4;
      *(float4*)(Bs + kk * 64 + cc) =
          *(const float4*)(X + (size_t)(k0 + kk) * DD + col0 + cc);
    }
    __syncthreads();
    #pragma unroll
    for (int k = 0; k < 32; ++k) {
      float av = Et[k * 16 + tm];
      float4 bv = *(const float4*)(Bs + k * 64 + tn * 4);
      #pragma unroll
      for (int j = 0; j < 4; ++j) acc[j] = fmaf(av, (&bv.x)[j], acc[j]);
    }
    __syncthreads();
  }
  const int p = row0 + tm;
  if (p < PP) {
    const float izv = rowIZ[tm], esv = rowES[tm];
    float4 sv = *(const float4*)(Pr + (size_t)p * DD + col0 + tn * 4);
    #pragma unroll
    for (int j = 0; j < 4; ++j)
      Mout[(size_t)p * DD + col0 + tn * 4 + j] = (acc[j] + esv * (&sv.x)[j]) * izv;
  }
}

// layer-1 mix: blocks [0,56) PROXY tiles FIRST (long poles start at t=0),
// then [56,312) sample tiles.
__global__ __launch_bounds__(NTHR) void mix1_k(
    const float* __restrict__ ls, const float* __restrict__ ld,
    const float* __restrict__ x, const float* __restrict__ prox,
    float* __restrict__ M1)
{
  __shared__ float smem[3648];
  const int b = blockIdx.x;
  if (b < 56)
    mixP_tile(ls, ld, x, prox, M1, (b >> 3) * 16, (b & 7) * 64, smem);
  else {
    int b2 = b - 56;
    mixS_tile(ls, ld, prox, x, M1 + (size_t)PP * DD,
              (b2 >> 3) * 32, (b2 & 7) * 64, smem);
  }
}

// layer-2 mix (sample dsts only; layer-2 proxy rows are dead code)
__global__ __launch_bounds__(NTHR) void mix2_k(
    const float* __restrict__ ls, const float* __restrict__ ld,
    const float* __restrict__ h1, float* __restrict__ M2)
{
  __shared__ float smem[3648];
  const int b = blockIdx.x;
  mixS_tile(ls, ld, h1, h1 + (size_t)PP * DD, M2, (b >> 3) * 32, (b & 7) * 64, smem);
}

// ---- one wave: dual dot of 512-float row with two 512-float vectors --------
__device__ __forceinline__ void dualdot(const float* __restrict__ row,
                                        const float* __restrict__ va,
                                        const float* __restrict__ vb,
                                        int lane, float* o1, float* o2)
{
  const float4* r4 = (const float4*)row;
  const float4* a4 = (const float4*)va;
  const float4* b4 = (const float4*)vb;
  float4 v0 = r4[lane], v1 = r4[lane + 64];
  float4 a0 = a4[lane], a1 = a4[lane + 64];
  float4 b0 = b4[lane], b1 = b4[lane + 64];
  float s1 = v0.x*a0.x + v0.y*a0.y + v0.z*a0.z + v0.w*a0.w
           + v1.x*a1.x + v1.y*a1.y + v1.z*a1.z + v1.w*a1.w;
  float s2 = v0.x*b0.x + v0.y*b0.y + v0.z*b0.z + v0.w*b0.w
           + v1.x*b1.x + v1.y*b1.y + v1.z*b1.z + v1.w*b1.w;
  #pragma unroll
  for (int off = 32; off > 0; off >>= 1) {
    s1 += __shfl_down(s1, off);
    s2 += __shfl_down(s2, off);
  }
  *o1 = s1; *o2 = s2;
}

// K1: v = W@a for both layers (1024 wave-rows) + zero ls2/ld2 (2304 floats)
__global__ __launch_bounds__(NTHR) void matvec_k(
    const float* __restrict__ W1, const float* __restrict__ as1,
    const float* __restrict__ ad1,
    const float* __restrict__ W2, const float* __restrict__ as2,
    const float* __restrict__ ad2,
    float* __restrict__ v1s, float* __restrict__ v1d,
    float* __restrict__ v2s, float* __restrict__ v2d,
    float* __restrict__ zbuf)
{
  const int wid  = blockIdx.x * 4 + (threadIdx.x >> 6);  // 0..1023
  const int lane = threadIdx.x & 63;
  const int r = wid & 511;
  const bool l1 = (wid < 512);
  float s1, s2;
  dualdot((l1 ? W1 : W2) + (size_t)r * DD, l1 ? as1 : as2, l1 ? ad1 : ad2,
          lane, &s1, &s2);
  if (lane == 0) { (l1 ? v1s : v2s)[r] = s1; (l1 ? v1d : v2d)[r] = s2; }
  for (int i = blockIdx.x * NTHR + threadIdx.x; i < 2304; i += 256 * NTHR)
    zbuf[i] = 0.f;
}

// K2: layer-1 logits (wave per row)
__global__ __launch_bounds__(NTHR) void lvec_k(
    const float* __restrict__ prox, const float* __restrict__ x,
    const float* __restrict__ vs, const float* __restrict__ vd,
    float* __restrict__ ls, float* __restrict__ ld)
{
  const int r    = blockIdx.x * 4 + (threadIdx.x >> 6);
  const int lane = threadIdx.x & 63;
  if (r >= NN) return;
  const float* row = (r < PP) ? prox + (size_t)r * DD : x + (size_t)(r - PP) * DD;
  float s1, s2;
  dualdot(row, vs, vd, lane, &s1, &s2);
  if (lane == 0) { ls[r] = s1; ld[r] = s2; }
}

extern "C" void kernel_launch(void* const* d_in, const int* in_sizes, int n_in,
                              void* d_out, int out_size, void* d_ws, size_t ws_size,
                              hipStream_t stream)
{
  const float* x    = (const float*)d_in[0];
  const float* prox = (const float*)d_in[1];
  const float* W1   = (const float*)d_in[2];
  const float* as1  = (const float*)d_in[3];
  const float* ad1  = (const float*)d_in[4];
  const float* b1   = (const float*)d_in[5];
  const float* W2   = (const float*)d_in[6];
  const float* as2  = (const float*)d_in[7];
  const float* ad2  = (const float*)d_in[8];
  const float* b2   = (const float*)d_in[9];
  const float* fcw  = (const float*)d_in[10];
  const float* fcb  = (const float*)d_in[11];
  float* out = (float*)d_out;

  float* h1  = (float*)d_ws;                     // [1124][512]
  float* M1  = h1  + (size_t)NN * DD;            // [1124][512]
  float* M2  = M1  + (size_t)NN * DD;            // [1024][512]
  float* ls1 = M2  + (size_t)NS * DD;            // [1152]
  float* ld1 = ls1 + 1152;
  float* ls2 = ld1 + 1152;                       // ls2/ld2 contiguous (zeroed in K1)
  float* ld2 = ls2 + 1152;
  float* v1s = ld2 + 1152;
  float* v1d = v1s + DD;
  float* v2s = v1d + DD;
  float* v2d = v2s + DD;
  float* h2s = out + (size_t)NS * CC;            // layer-2 sample out in d_out

  dim3 blk(NTHR);
  // K1: weight-side matvecs (both layers) + zero ls2/ld2
  matvec_k<<<dim3(256), blk, 0, stream>>>(W1, as1, ad1, W2, as2, ad2,
                                          v1s, v1d, v2s, v2d, ls2);
  // K2: layer-1 logits
  lvec_k<<<dim3(281), blk, 0, stream>>>(prox, x, v1s, v1d, ls1, ld1);
  // K3: layer-1 mix (proxy tiles first, then sample tiles) -> M1
  mix1_k<<<dim3(312), blk, 0, stream>>>(ls1, ld1, x, prox, M1);
  // K4: h1 = relu(M1@W1 + b1); epilogue fuses layer-2 logits into ls2/ld2
  gemm_k<32, 64, 2, true, true><<<dim3(8, 36), blk, 0, stream>>>(
      M1, NN, W1, h1, b1, DD, DD, v2s, v2d, ls2, ld2);
  // K5: layer-2 mix (sample dsts only) -> M2
  mix2_k<<<dim3(256), blk, 0, stream>>>(ls2, ld2, h1, M2);
  // K6: h2s = relu(M2@W2 + b2) straight into d_out
  gemm_k<32, 64, 2, true, false><<<dim3(8, 32), blk, 0, stream>>>(
      M2, NS, W2, h2s, b2, DD, DD, nullptr, nullptr, nullptr, nullptr);
  // K7: preds = h2s @ fcw + fcb   (16-row tiles for parallelism: 2 x 64)
  gemm_k<16, 64, 1, false, false><<<dim3(2, 64), blk, 0, stream>>>(
      h2s, NS, fcw, out, fcb, DD, CC, nullptr, nullptr, nullptr, nullptr);
}